// Round 3
// baseline (216.768 us; speedup 1.0000x reference)
//
#include <hip/hip_runtime.h>

constexpr int IN_DIM = 128;
constexpr int OUT_DIM = 64;
constexpr int EDGE_DIM = 16;
constexpr int BS = 8;
constexpr int NN = 512;
constexpr int ROWS = BS * NN;   // 4096
constexpr int TI = 4;           // attention rows per block

typedef float f32x4 __attribute__((ext_vector_type(4)));

// ---------------------------------------------------------------------------
// Kernel 1: h = x @ W^T (row-major h: (ROWS,64)), s_i = h·a_i, s_j = h·a_j
// ---------------------------------------------------------------------------
__global__ __launch_bounds__(256, 4) void fc_kernel(
    const float* __restrict__ x, const float* __restrict__ W,
    const float* __restrict__ attn_w,
    float* __restrict__ h, float* __restrict__ si, float* __restrict__ sj)
{
    __shared__ float xs[8 * IN_DIM];      // 8 rows x 128 = 4 KB
    const int t    = threadIdx.x;
    const int lane = t & 63;              // output dim o
    const int w    = t >> 6;              // wave id 0..3
    const int rowBase = blockIdx.x * 8;

    ((float4*)xs)[t] = ((const float4*)(x + (size_t)rowBase * IN_DIM))[t];

    const float a_i = attn_w[lane];
    const float a_j = attn_w[OUT_DIM + lane];
    __syncthreads();

    const float4* W4 = (const float4*)W;  // row o at W4[o*32 + k]
    float acc0 = 0.f, acc1 = 0.f;
    const float4* xr0 = (const float4*)&xs[(w * 2 + 0) * IN_DIM];
    const float4* xr1 = (const float4*)&xs[(w * 2 + 1) * IN_DIM];
    #pragma unroll 8
    for (int k = 0; k < IN_DIM / 4; ++k) {
        const float4 wv = W4[lane * (IN_DIM / 4) + k];
        const float4 x0 = xr0[k];
        const float4 x1 = xr1[k];
        acc0 += x0.x * wv.x + x0.y * wv.y + x0.z * wv.z + x0.w * wv.w;
        acc1 += x1.x * wv.x + x1.y * wv.y + x1.z * wv.z + x1.w * wv.w;
    }
    #pragma unroll
    for (int r = 0; r < 2; ++r) {
        const float a   = r ? acc1 : acc0;
        const int   row = rowBase + w * 2 + r;
        h[(size_t)row * OUT_DIM + lane] = a;
        float pi = a * a_i;
        float pj = a * a_j;
        #pragma unroll
        for (int m = 32; m > 0; m >>= 1) {
            pi += __shfl_xor(pi, m, 64);
            pj += __shfl_xor(pj, m, 64);
        }
        if (lane == 0) { si[row] = pi; sj[row] = pj; }
    }
}

// ---------------------------------------------------------------------------
// Kernel 2: TI=4 rows per block, wave w owns row w. Phase 1 now reads edge
// with one CONTIGUOUS float4 per lane (wave = 1 KB/instr, nontemporal) and
// reduces the 16-elem edge dot across 4-lane groups via shfl_xor.
// Pre-softmax e -> LDS (wave-local), softmax via shfl butterflies,
// normalized alpha -> LDS, then block-wide alpha x h (h read once/block).
// ---------------------------------------------------------------------------
__global__ __launch_bounds__(256, 4) void attn_kernel(
    const float* __restrict__ edge, const float* __restrict__ attn_w,
    const float* __restrict__ h, const float* __restrict__ si,
    const float* __restrict__ sj, float* __restrict__ out)
{
    __shared__ float  ebuf[TI * NN];      // 8 KB: pre-softmax e, then alpha
    __shared__ float4 part[TI][16][16];   // 16 KB

    const int t    = threadIdx.x;
    const int lane = t & 63;
    const int w    = t >> 6;              // wave = local row r
    const int blk  = blockIdx.x;          // b*128 + itile
    const int b    = blk >> 7;
    const int iRow = (blk & 127) * TI + w;
    const int rowg = (b << 9) + iRow;

    // a_e quarter for this lane (c = lane & 3), via cndmask chains
    const float4* ae4 = (const float4*)(attn_w + 2 * OUT_DIM);
    const float4 ae0 = ae4[0], ae1 = ae4[1], ae2 = ae4[2], ae3 = ae4[3];
    const float4 aeLo = (lane & 1) ? ae1 : ae0;
    const float4 aeHi = (lane & 1) ? ae3 : ae2;
    const float4 aeSel = (lane & 2) ? aeHi : aeLo;

    const float  siv = si[rowg];
    const float* sjb = sj + (b << 9);
    const f32x4* ef4 = (const f32x4*)edge + (size_t)rowg * (NN * EDGE_DIM / 4);

    // ---- phase 1: 32 iterations x 16 j's; contiguous nontemporal loads ----
    #pragma unroll 8
    for (int it = 0; it < 32; ++it) {
        const int jbase = it * 16;
        const f32x4 v = __builtin_nontemporal_load(ef4 + jbase * 4 + lane);
        float p = v.x * aeSel.x + v.y * aeSel.y + v.z * aeSel.z + v.w * aeSel.w;
        p += __shfl_xor(p, 1, 64);
        p += __shfl_xor(p, 2, 64);        // full edge-dot in all 4 lanes
        if ((lane & 3) == 0) {
            const int j = jbase + (lane >> 2);
            ebuf[w * NN + j] = siv + sjb[j] + p;
        }
    }

    // ---- wave-local softmax (same wave wrote ebuf; no barrier needed) ----
    float e[8];
    #pragma unroll
    for (int jj = 0; jj < 8; ++jj) e[jj] = ebuf[w * NN + jj * 64 + lane];
    float m = e[0];
    #pragma unroll
    for (int jj = 1; jj < 8; ++jj) m = fmaxf(m, e[jj]);
    #pragma unroll
    for (int msk = 32; msk > 0; msk >>= 1) m = fmaxf(m, __shfl_xor(m, msk, 64));

    float p[8], s = 0.f;
    #pragma unroll
    for (int jj = 0; jj < 8; ++jj) { p[jj] = __expf(e[jj] - m); s += p[jj]; }
    #pragma unroll
    for (int msk = 32; msk > 0; msk >>= 1) s += __shfl_xor(s, msk, 64);
    const float rinv = 1.0f / s;
    #pragma unroll
    for (int jj = 0; jj < 8; ++jj)
        ebuf[w * NN + jj * 64 + lane] = p[jj] * rinv;

    __syncthreads();

    // ---- phase 3: out[r,:] = sum_j alpha[r][j] * h[b,j,:], h read once ----
    const int o4 = t & 15;                // float4 chunk of 64-dim output
    const int g  = t >> 4;                // 16 groups over j
    const float4* h4 = (const float4*)(h + ((size_t)(b << 9)) * OUT_DIM);
    float4 acc[TI];
    #pragma unroll
    for (int r = 0; r < TI; ++r) acc[r] = make_float4(0.f, 0.f, 0.f, 0.f);
    #pragma unroll 4
    for (int j = g; j < NN; j += 16) {
        const float4 hv = h4[j * 16 + o4];
        #pragma unroll
        for (int r = 0; r < TI; ++r) {
            const float a = ebuf[r * NN + j];     // 16-lane broadcast
            acc[r].x += a * hv.x; acc[r].y += a * hv.y;
            acc[r].z += a * hv.z; acc[r].w += a * hv.w;
        }
    }
    #pragma unroll
    for (int r = 0; r < TI; ++r) part[r][g][o4] = acc[r];
    __syncthreads();

    if (t < 64) {
        const int r = t >> 4, c = t & 15;
        float4 v = part[r][0][c];
        #pragma unroll
        for (int g2 = 1; g2 < 16; ++g2) {
            const float4 q = part[r][g2][c];
            v.x += q.x; v.y += q.y; v.z += q.z; v.w += q.w;
        }
        ((float4*)out)[((size_t)(b << 9) + (blk & 127) * TI + r) * 16 + c] = v;
    }
}

extern "C" void kernel_launch(void* const* d_in, const int* in_sizes, int n_in,
                              void* d_out, int out_size, void* d_ws, size_t ws_size,
                              hipStream_t stream) {
    const float* x      = (const float*)d_in[0];
    const float* edge   = (const float*)d_in[1];
    const float* W_fc   = (const float*)d_in[2];
    const float* attn_w = (const float*)d_in[3];
    float* out = (float*)d_out;

    float* h  = (float*)d_ws;             // ROWS*64 floats = 1 MiB
    float* si = h + (size_t)ROWS * OUT_DIM;
    float* sj = si + ROWS;

    fc_kernel<<<ROWS / 8, 256, 0, stream>>>(x, W_fc, attn_w, h, si, sj);
    attn_kernel<<<ROWS / TI, 256, 0, stream>>>(edge, attn_w, h, si, sj, out);
}